// Round 1
// baseline (92.142 us; speedup 1.0000x reference)
//
#include <hip/hip_runtime.h>

// 5x5 median filter, reflect padding, NHWC float32.
// Exact median-of-25 via forgetful selection with a 14-element buffer:
//   repeatedly remove the buffer's min and max (both provably cannot be the
//   global median while buffer size >= safety bound), refill with unseen
//   elements; shrink at the end down to a median-of-3.
// 175 compare-exchange ops per output element.

#define CAS(a, b) do { float _t = fminf(a, b); (b) = fmaxf(a, b); (a) = _t; } while (0)

__device__ __forceinline__ void mm14(float* e) {
  // min -> e[0], max -> e[13], middle 12 in e[1..12]
  CAS(e[0], e[1]);  CAS(e[2], e[3]);  CAS(e[4], e[5]);  CAS(e[6], e[7]);
  CAS(e[8], e[9]);  CAS(e[10], e[11]); CAS(e[12], e[13]);
  CAS(e[0], e[2]);  CAS(e[4], e[6]);  CAS(e[8], e[10]);
  CAS(e[0], e[4]);  CAS(e[8], e[12]); CAS(e[0], e[8]);
  CAS(e[1], e[3]);  CAS(e[5], e[7]);  CAS(e[9], e[11]);
  CAS(e[3], e[7]);  CAS(e[11], e[13]); CAS(e[7], e[13]);
}

__global__ __launch_bounds__(256) void median5x5_kernel(
    const float* __restrict__ x, float* __restrict__ out, int total) {
  int t = blockIdx.x * blockDim.x + threadIdx.x;
  if (t >= total) return;

  const int C = 3, W = 384, H = 384;

  int c   = t % C;
  int pix = t / C;
  int w   = pix % W;
  int hb  = pix / W;
  int h   = hb % H;
  int b   = hb / H;

  // Reflected row indices and column element-offsets.
  int rh[5], ow[5];
#pragma unroll
  for (int i = 0; i < 5; ++i) {
    int v = h + i - 2;
    v = v < 0 ? -v : v;
    v = v >= H ? 2 * H - 2 - v : v;
    rh[i] = v;
    int u = w + i - 2;
    u = u < 0 ? -u : u;
    u = u >= W ? 2 * W - 2 - u : u;
    ow[i] = u * C;
  }

  const float* base = x + (size_t)b * H * W * C + c;

  float e[25];
#pragma unroll
  for (int i = 0; i < 5; ++i) {
    const float* row = base + (size_t)rh[i] * (W * C);
#pragma unroll
    for (int j = 0; j < 5; ++j) e[i * 5 + j] = row[ow[j]];
  }

  // ---- forgetful selection: exact median of 25 (rank 13) ----
  // Rounds on a 14-slot buffer e[0..13]; refill discarded slots.
  mm14(e); e[0] = e[14]; e[13] = e[15];
  mm14(e); e[0] = e[16]; e[13] = e[17];
  mm14(e); e[0] = e[18]; e[13] = e[19];
  mm14(e); e[0] = e[20]; e[13] = e[21];
  mm14(e); e[0] = e[22]; e[13] = e[23];
  mm14(e); e[0] = e[24];            // buffer = e[0..12] (13 elems)

  // mm13 on e[0..12]: min->e[0], max->e[12], buffer -> e[1..11]
  CAS(e[0], e[1]);  CAS(e[2], e[3]);  CAS(e[4], e[5]);
  CAS(e[6], e[7]);  CAS(e[8], e[9]);  CAS(e[10], e[11]);
  CAS(e[0], e[12]);                              // fold odd slot
  CAS(e[0], e[2]);  CAS(e[4], e[6]);  CAS(e[8], e[10]);
  CAS(e[0], e[4]);  CAS(e[0], e[8]);
  CAS(e[1], e[3]);  CAS(e[5], e[7]);  CAS(e[9], e[11]);
  CAS(e[3], e[7]);  CAS(e[11], e[12]); CAS(e[7], e[12]);

  // mm11 on e[1..11]: min->e[1], max->e[11], buffer -> e[2..10]
  CAS(e[1], e[2]);  CAS(e[3], e[4]);  CAS(e[5], e[6]);
  CAS(e[7], e[8]);  CAS(e[9], e[10]);
  CAS(e[1], e[11]);
  CAS(e[1], e[3]);  CAS(e[5], e[7]);
  CAS(e[1], e[5]);  CAS(e[1], e[9]);
  CAS(e[2], e[4]);  CAS(e[6], e[8]);  CAS(e[10], e[11]);
  CAS(e[4], e[8]);  CAS(e[8], e[11]);

  // mm9 on e[2..10]: min->e[2], max->e[10], buffer -> e[3..9]
  CAS(e[2], e[3]);  CAS(e[4], e[5]);  CAS(e[6], e[7]);  CAS(e[8], e[9]);
  CAS(e[2], e[10]);
  CAS(e[2], e[4]);  CAS(e[6], e[8]);  CAS(e[2], e[6]);
  CAS(e[3], e[5]);  CAS(e[7], e[9]);  CAS(e[5], e[9]);  CAS(e[9], e[10]);

  // mm7 on e[3..9]: min->e[3], max->e[9], buffer -> e[4..8]
  CAS(e[3], e[4]);  CAS(e[5], e[6]);  CAS(e[7], e[8]);
  CAS(e[3], e[9]);
  CAS(e[3], e[5]);  CAS(e[3], e[7]);
  CAS(e[4], e[6]);  CAS(e[8], e[9]);  CAS(e[6], e[9]);

  // mm5 on e[4..8]: min->e[4], max->e[8], buffer -> e[5..7]
  CAS(e[4], e[5]);  CAS(e[6], e[7]);
  CAS(e[4], e[8]);
  CAS(e[4], e[6]);
  CAS(e[5], e[7]);  CAS(e[7], e[8]);

  // median of 3 (e[5..7])
  CAS(e[5], e[6]);
  out[t] = fmaxf(e[5], fminf(e[6], e[7]));
}

extern "C" void kernel_launch(void* const* d_in, const int* in_sizes, int n_in,
                              void* d_out, int out_size, void* d_ws, size_t ws_size,
                              hipStream_t stream) {
  const float* x = (const float*)d_in[0];
  float* out = (float*)d_out;
  int total = out_size;  // 16*384*384*3 = 7,077,888
  int block = 256;
  int grid = (total + block - 1) / block;
  median5x5_kernel<<<grid, block, 0, stream>>>(x, out, total);
}

// Round 2
// 43.688 us; speedup vs baseline: 2.1091x; 2.1091x over previous
//
#include <hip/hip_runtime.h>

// 5x5 median, reflect padding, NHWC f32 (16,384,384,3).
// Thread = (b, w, c) x run of RUN outputs along h.
// - Horizontal 5-windows sorted once per row, shared by 5 vertical outputs.
// - Per output: column-sort the 5 sorted rows (2D-sort, shear lemma), then
//   exact median = rank-7 of the 13-cell candidate band (forgetful selection
//   seeded with the band's known partial order).

#define CAS(a, b) do { float _t = fminf(a, b); (b) = fmaxf(a, b); (a) = _t; } while (0)

// Optimal 9-CAS sorting network for 5 elements.
#define SORT5(e0, e1, e2, e3, e4) do { \
  CAS(e0, e1); CAS(e3, e4); CAS(e2, e4); CAS(e2, e3); CAS(e1, e4); \
  CAS(e0, e3); CAS(e0, e2); CAS(e1, e3); CAS(e1, e2); } while (0)

__device__ __forceinline__ int reflect_idx(int v, int n) {
  v = v < 0 ? -v : v;
  v = v >= n ? 2 * n - 2 - v : v;
  return v;
}

constexpr int RUN = 8;

__global__ __launch_bounds__(256) void median5x5_kernel(
    const float* __restrict__ x, float* __restrict__ out, int total_threads) {
  int t = blockIdx.x * blockDim.x + threadIdx.x;
  if (t >= total_threads) return;

  const int C = 3, W = 384, H = 384;
  const int HB = H / RUN;
  const int WC = W * C;

  // lanes enumerate c fastest, then w -> every tap load / store coalesced
  int c = t % C;
  int rest = t / C;
  int w = rest % W;
  rest /= W;
  int hb = rest % HB;
  int b = rest / HB;
  int h0 = hb * RUN;

  // reflected column offsets (fixed per thread)
  int ow0 = reflect_idx(w - 2, W) * C;
  int ow1 = reflect_idx(w - 1, W) * C;
  int ow2 = w * C;
  int ow3 = reflect_idx(w + 1, W) * C;
  int ow4 = reflect_idx(w + 2, W) * C;

  const float* base = x + (size_t)b * H * WC + c;

  float rows[5][5];  // ring of sorted 5-windows; slot order irrelevant for median

  // prologue: rows h0-2 .. h0+1 -> slots 0..3
#pragma unroll
  for (int p = 0; p < 4; ++p) {
    const float* rp = base + (size_t)reflect_idx(h0 - 2 + p, H) * WC;
    float e0 = rp[ow0], e1 = rp[ow1], e2 = rp[ow2], e3 = rp[ow3], e4 = rp[ow4];
    SORT5(e0, e1, e2, e3, e4);
    rows[p][0] = e0; rows[p][1] = e1; rows[p][2] = e2; rows[p][3] = e3; rows[p][4] = e4;
  }

  size_t obase = ((size_t)b * H + h0) * WC + (size_t)w * C + c;

#pragma unroll
  for (int k = 0; k < RUN; ++k) {
    // load + sort the incoming row into the oldest ring slot
    {
      const float* rp = base + (size_t)reflect_idx(h0 + k + 2, H) * WC;
      float e0 = rp[ow0], e1 = rp[ow1], e2 = rp[ow2], e3 = rp[ow3], e4 = rp[ow4];
      SORT5(e0, e1, e2, e3, e4);
      const int s = (k + 4) % 5;  // compile-time after unroll
      rows[s][0] = e0; rows[s][1] = e1; rows[s][2] = e2; rows[s][3] = e3; rows[s][4] = e4;
    }

    // working copy; column sort (rows stay sorted by the shear lemma -> 2D-sorted)
    float m[5][5];
#pragma unroll
    for (int i = 0; i < 5; ++i)
#pragma unroll
      for (int j = 0; j < 5; ++j) m[i][j] = rows[i][j];
#pragma unroll
    for (int j = 0; j < 5; ++j) SORT5(m[0][j], m[1][j], m[2][j], m[3][j], m[4][j]);

    // 13-candidate band (cells with (i+1)(j+1)<=13 and (5-i)(5-j)<=13)
    float A1 = m[0][3], A2 = m[0][4];
    float B1 = m[1][2], B2 = m[1][3], B3 = m[1][4];
    float C1 = m[2][1], C2 = m[2][2], C3 = m[2][3];
    float D1 = m[3][0], D2 = m[3][1], D3 = m[3][2];
    float E1 = m[4][0], E2 = m[4][1];

    // forgetful selection for rank 7 of 13, seeded with band partial order
    // round 1: buffer {A1,A2,B1,B2,B3,C1,C2,C3}; max in {B3,C3} (A2<=B3), min in {A1,B1,C1}
    CAS(B3, C3);               // C3 = max -> discard
    CAS(A1, B1); CAS(A1, C1);  // A1 = min -> discard
    // round 2: buffer {A2,B1,B2,B3,C1,C2,D1,D2}; knowns B1<=B2<=B3, C1<=C2, D1<=D2
    CAS(A2, B3); CAS(C2, D2); CAS(B3, D2);  // D2 = max -> discard
    CAS(B1, C1); CAS(D1, A2); CAS(B1, D1);  // B1 = min -> discard
    // round 3: generic min/max-of-8 on survivors {C1,B2,B3,C2,A2,D1} + {D3,E1}
    float s0 = C1, s1 = B2, s2 = B3, s3 = C2, s4 = A2, s5 = D1, s6 = D3, s7 = E1;
    CAS(s0, s1); CAS(s2, s3); CAS(s4, s5); CAS(s6, s7);
    CAS(s0, s2); CAS(s4, s6); CAS(s0, s4);  // s0 = min -> discard
    CAS(s1, s3); CAS(s5, s7); CAS(s3, s7);  // s7 = max -> discard
    // round 4: min/max-of-7 on {s1..s6} + {E2}
    float t0 = s1, t1 = s2, t2 = s3, t3 = s4, t4 = s5, t5 = s6, t6 = E2;
    CAS(t0, t1); CAS(t2, t3); CAS(t4, t5);
    CAS(t0, t2); CAS(t0, t4); CAS(t0, t6);  // t0 = min -> discard
    CAS(t1, t3); CAS(t5, t6); CAS(t3, t6);  // t6 = max -> discard
    // round 5: min/max-of-5 on {t1..t5}
    CAS(t1, t2); CAS(t3, t4);
    CAS(t1, t3); CAS(t1, t5);  // t1 = min -> discard
    CAS(t2, t4); CAS(t4, t5);  // t5 = max -> discard
    // median of remaining 3 {t2,t3,t4}
    CAS(t2, t3);
    out[obase + (size_t)k * WC] = fmaxf(t2, fminf(t3, t4));
  }
}

extern "C" void kernel_launch(void* const* d_in, const int* in_sizes, int n_in,
                              void* d_out, int out_size, void* d_ws, size_t ws_size,
                              hipStream_t stream) {
  const float* x = (const float*)d_in[0];
  float* out = (float*)d_out;
  const int B = 16, H = 384, W = 384, C = 3;
  int total_threads = B * (H / RUN) * W * C;  // 884,736
  int block = 256;
  int grid = (total_threads + block - 1) / block;
  median5x5_kernel<<<grid, block, 0, stream>>>(x, out, total_threads);
}

// Round 3
// 42.926 us; speedup vs baseline: 2.1465x; 1.0178x over previous
//
#include <hip/hip_runtime.h>

// 5x5 median, reflect padding, NHWC f32 (16,384,384,3).
// Thread = (b, w, c) x RUN outputs along h.
// - Sorted-row ring (each horizontal 5-window sorted once, reused 5x).
// - Prefetch next row's 5 taps one iteration ahead (latency hidden under math).
// - Column stage: sort4 of old rows + closed-form rank-insert of the new row,
//   computing ONLY the 13 band cells (exact order statistics per column).
// - Exact median = rank-7 of the 13-cell band (forgetful selection seeded
//   with the band's lattice order).

#define CAS(a, b) do { float _t = fminf(a, b); (b) = fmaxf(a, b); (a) = _t; } while (0)

#define SORT5(e0, e1, e2, e3, e4) do { \
  CAS(e0, e1); CAS(e3, e4); CAS(e2, e4); CAS(e2, e3); CAS(e1, e4); \
  CAS(e0, e3); CAS(e0, e2); CAS(e1, e3); CAS(e1, e2); } while (0)

#define SORT4(a, b, c, d) do { \
  CAS(a, b); CAS(c, d); CAS(a, c); CAS(b, d); CAS(b, c); } while (0)

__device__ __forceinline__ int reflect_idx(int v, int n) {
  v = v < 0 ? -v : v;
  v = v >= n ? 2 * n - 2 - v : v;
  return v;
}

constexpr int RUN = 8;

__global__ __launch_bounds__(256, 4) void median5x5_kernel(
    const float* __restrict__ x, float* __restrict__ out, int total_threads) {
  int t = blockIdx.x * blockDim.x + threadIdx.x;
  if (t >= total_threads) return;

  const int C = 3, W = 384, H = 384;
  const int HB = H / RUN;
  const int WC = W * C;

  int c = t % C;
  int rest = t / C;
  int w = rest % W;
  rest /= W;
  int hb = rest % HB;
  int b = rest / HB;
  int h0 = hb * RUN;

  int ow0 = reflect_idx(w - 2, W) * C;
  int ow1 = reflect_idx(w - 1, W) * C;
  int ow2 = w * C;
  int ow3 = reflect_idx(w + 1, W) * C;
  int ow4 = reflect_idx(w + 2, W) * C;

  const float* base = x + b * H * WC + c;  // fits in int32 (28M elements)

  float r[5][5];  // ring of sorted 5-windows

  // prologue: rows h0-2 .. h0+1 -> slots 0..3
#pragma unroll
  for (int p = 0; p < 4; ++p) {
    const float* rp = base + reflect_idx(h0 - 2 + p, H) * WC;
    float e0 = rp[ow0], e1 = rp[ow1], e2 = rp[ow2], e3 = rp[ow3], e4 = rp[ow4];
    SORT5(e0, e1, e2, e3, e4);
    r[p][0] = e0; r[p][1] = e1; r[p][2] = e2; r[p][3] = e3; r[p][4] = e4;
  }

  // prefetch first compute row (h0+2), raw
  float p0, p1, p2, p3, p4;
  {
    const float* rp = base + reflect_idx(h0 + 2, H) * WC;
    p0 = rp[ow0]; p1 = rp[ow1]; p2 = rp[ow2]; p3 = rp[ow3]; p4 = rp[ow4];
  }

  int orow = (b * H + h0) * WC + w * C + c;

#pragma unroll
  for (int k = 0; k < RUN; ++k) {
    // sort the prefetched row into ring slot s
    float n0 = p0, n1 = p1, n2 = p2, n3 = p3, n4 = p4;
    SORT5(n0, n1, n2, n3, n4);
    const int s = (k + 4) % 5;  // compile-time after unroll
    r[s][0] = n0; r[s][1] = n1; r[s][2] = n2; r[s][3] = n3; r[s][4] = n4;

    // prefetch next row (consumed next iteration; latency hides under math)
    if (k + 1 < RUN) {
      const float* rp = base + reflect_idx(h0 + k + 3, H) * WC;
      p0 = rp[ow0]; p1 = rp[ow1]; p2 = rp[ow2]; p3 = rp[ow3]; p4 = rp[ow4];
    }

    const int q0 = (s + 1) % 5, q1 = (s + 2) % 5, q2 = (s + 3) % 5, q3 = (s + 4) % 5;

    // ---- column stage: 13 band cells, exact per-column order statistics ----
    float A1, A2, B1, B2, B3, Cc1, Cc2, Cc3, D1, D2, D3, E1, E2;
    {  // col 0: ranks 3,4
      float a = r[q0][0], bb = r[q1][0], cc = r[q2][0], d = r[q3][0], e = n0;
      SORT4(a, bb, cc, d);
      D1 = fmaxf(cc, fminf(d, e));
      E1 = fmaxf(d, e);
    }
    {  // col 1: ranks 2,3,4
      float a = r[q0][1], bb = r[q1][1], cc = r[q2][1], d = r[q3][1], e = n1;
      SORT4(a, bb, cc, d);
      Cc1 = fmaxf(bb, fminf(cc, e));
      D2  = fmaxf(cc, fminf(d, e));
      E2  = fmaxf(d, e);
    }
    {  // col 2: ranks 1,2,3
      float a = r[q0][2], bb = r[q1][2], cc = r[q2][2], d = r[q3][2], e = n2;
      SORT4(a, bb, cc, d);
      B1 = fmaxf(a,  fminf(bb, e));
      Cc2 = fmaxf(bb, fminf(cc, e));
      D3 = fmaxf(cc, fminf(d, e));
    }
    {  // col 3: ranks 0,1,2
      float a = r[q0][3], bb = r[q1][3], cc = r[q2][3], d = r[q3][3], e = n3;
      SORT4(a, bb, cc, d);
      A1 = fminf(a, e);
      B2 = fminf(bb, fmaxf(a, e));
      Cc3 = fminf(cc, fmaxf(bb, e));
    }
    {  // col 4: ranks 0,1
      float a = r[q0][4], bb = r[q1][4], cc = r[q2][4], d = r[q3][4], e = n4;
      SORT4(a, bb, cc, d);
      A2 = fminf(a, e);
      B3 = fminf(bb, fmaxf(a, e));
    }

    // ---- forgetful selection for rank 7 of 13 (band lattice order) ----
    CAS(B3, Cc3);                 // Cc3 = max -> discard
    CAS(A1, B1); CAS(A1, Cc1);    // A1 = min -> discard
    CAS(A2, B3); CAS(Cc2, D2); CAS(B3, D2);   // D2 = max -> discard
    CAS(B1, Cc1); CAS(D1, A2); CAS(B1, D1);   // B1 = min -> discard
    float s0 = Cc1, s1 = B2, s2 = B3, s3 = Cc2, s4 = A2, s5 = D1, s6 = D3, s7 = E1;
    CAS(s0, s1); CAS(s2, s3); CAS(s4, s5); CAS(s6, s7);
    CAS(s0, s2); CAS(s4, s6); CAS(s0, s4);    // s0 = min -> discard
    CAS(s1, s3); CAS(s5, s7); CAS(s3, s7);    // s7 = max -> discard
    float t0 = s1, t1 = s2, t2 = s3, t3 = s4, t4 = s5, t5 = s6, t6 = E2;
    CAS(t0, t1); CAS(t2, t3); CAS(t4, t5);
    CAS(t0, t2); CAS(t0, t4); CAS(t0, t6);    // t0 = min -> discard
    CAS(t1, t3); CAS(t5, t6); CAS(t3, t6);    // t6 = max -> discard
    CAS(t1, t2); CAS(t3, t4);
    CAS(t1, t3); CAS(t1, t5);                 // t1 = min -> discard
    CAS(t2, t4); CAS(t4, t5);                 // t5 = max -> discard
    CAS(t2, t3);
    out[orow + k * WC] = fmaxf(t2, fminf(t3, t4));
  }
}

extern "C" void kernel_launch(void* const* d_in, const int* in_sizes, int n_in,
                              void* d_out, int out_size, void* d_ws, size_t ws_size,
                              hipStream_t stream) {
  const float* x = (const float*)d_in[0];
  float* out = (float*)d_out;
  const int B = 16, H = 384, W = 384, C = 3;
  int total_threads = B * (H / RUN) * W * C;  // 884,736
  int block = 256;
  int grid = (total_threads + block - 1) / block;
  median5x5_kernel<<<grid, block, 0, stream>>>(x, out, total_threads);
}

// Round 4
// 42.603 us; speedup vs baseline: 2.1628x; 1.0076x over previous
//
#include <hip/hip_runtime.h>

// 5x5 median, reflect padding, NHWC f32 (16,384,384,3).
// Interior thread = 4 consecutive flat elements (f..f+3, f%4==0) x RUN rows.
//   - 5 aligned float4 loads per row cover all 4 columns' 5-tap windows.
//   - Sorted-row ring per column (5 slots), reused by 5 vertical outputs.
//   - Column stage: SORT4 of old rows + closed-form rank-insert of new row,
//     only the 13 band cells (exact order statistics). [validated R2/R3]
//   - Exact median = rank-7 of 13-cell band, forgetful selection. [validated]
//   - float4 output store.
// Border columns (w within 2 of edge: flat 0..7, 1144..1151) handled by 96
// dedicated trailing blocks (block-uniform branch, scalar gather w/ reflect).

#define CAS(a, b) do { float _t = fminf(a, b); (b) = fmaxf(a, b); (a) = _t; } while (0)

#define SORT5(e0, e1, e2, e3, e4) do { \
  CAS(e0, e1); CAS(e3, e4); CAS(e2, e4); CAS(e2, e3); CAS(e1, e4); \
  CAS(e0, e3); CAS(e0, e2); CAS(e1, e3); CAS(e1, e2); } while (0)

#define SORT4(a, b, c, d) do { \
  CAS(a, b); CAS(c, d); CAS(a, c); CAS(b, d); CAS(b, c); } while (0)

__device__ __forceinline__ int reflect_idx(int v, int n) {
  v = v < 0 ? -v : v;
  v = v >= n ? 2 * n - 2 - v : v;
  return v;
}

// Exact median of 25: rows a,b,c,d = the 4 older sorted 5-windows (any order),
// n = newest sorted 5-window. Column stage + band selection (validated R2/R3).
__device__ __forceinline__ float median25(const float* a, const float* b,
                                          const float* cc, const float* d,
                                          const float* n) {
  float A1, A2, B1, B2, B3, C1, C2, C3, D1, D2, D3, E1, E2;
  { float p=a[0],q=b[0],r=cc[0],s=d[0],e=n[0]; SORT4(p,q,r,s);
    D1 = fmaxf(r, fminf(s, e)); E1 = fmaxf(s, e); }
  { float p=a[1],q=b[1],r=cc[1],s=d[1],e=n[1]; SORT4(p,q,r,s);
    C1 = fmaxf(q, fminf(r, e)); D2 = fmaxf(r, fminf(s, e)); E2 = fmaxf(s, e); }
  { float p=a[2],q=b[2],r=cc[2],s=d[2],e=n[2]; SORT4(p,q,r,s);
    B1 = fmaxf(p, fminf(q, e)); C2 = fmaxf(q, fminf(r, e)); D3 = fmaxf(r, fminf(s, e)); }
  { float p=a[3],q=b[3],r=cc[3],s=d[3],e=n[3]; SORT4(p,q,r,s);
    A1 = fminf(p, e); B2 = fminf(q, fmaxf(p, e)); C3 = fminf(r, fmaxf(q, e)); }
  { float p=a[4],q=b[4],r=cc[4],s=d[4],e=n[4]; SORT4(p,q,r,s);
    A2 = fminf(p, e); B3 = fminf(q, fmaxf(p, e)); }

  CAS(B3, C3);
  CAS(A1, B1); CAS(A1, C1);
  CAS(A2, B3); CAS(C2, D2); CAS(B3, D2);
  CAS(B1, C1); CAS(D1, A2); CAS(B1, D1);
  float s0 = C1, s1 = B2, s2 = B3, s3 = C2, s4 = A2, s5 = D1, s6 = D3, s7 = E1;
  CAS(s0, s1); CAS(s2, s3); CAS(s4, s5); CAS(s6, s7);
  CAS(s0, s2); CAS(s4, s6); CAS(s0, s4);
  CAS(s1, s3); CAS(s5, s7); CAS(s3, s7);
  float t0 = s1, t1 = s2, t2 = s3, t3 = s4, t4 = s5, t5 = s6, t6 = E2;
  CAS(t0, t1); CAS(t2, t3); CAS(t4, t5);
  CAS(t0, t2); CAS(t0, t4); CAS(t0, t6);
  CAS(t1, t3); CAS(t5, t6); CAS(t3, t6);
  CAS(t1, t2); CAS(t3, t4);
  CAS(t1, t3); CAS(t1, t5);
  CAS(t2, t4); CAS(t4, t5);
  CAS(t2, t3);
  return fmaxf(t2, fminf(t3, t4));
}

constexpr int RUN = 4;
constexpr int Bn = 16, Hn = 384, Wn = 384, Cn = 3;
constexpr int WC = Wn * Cn;            // 1152
constexpr int HB = Hn / RUN;           // 96
constexpr int NG_I = 284;              // interior groups: f = 4*gi + 8, gi in [0,284)
constexpr int N_INT = Bn * HB * NG_I;  // 436224 = 1704 * 256
constexpr int N_BND = Bn * HB * 16;    // 24576  = 96 * 256

__device__ __forceinline__ void load20(const float* rowbase, float* L) {
  const float4* rp = reinterpret_cast<const float4*>(rowbase);
#pragma unroll
  for (int q = 0; q < 5; ++q)
    reinterpret_cast<float4*>(L)[q] = rp[q];
}

__device__ __forceinline__ void sort_into(float r[4][5][5], const float* L, int slot) {
#pragma unroll
  for (int i = 0; i < 4; ++i) {
    float e0 = L[i + 2], e1 = L[i + 5], e2 = L[i + 8], e3 = L[i + 11], e4 = L[i + 14];
    SORT5(e0, e1, e2, e3, e4);
    r[i][slot][0] = e0; r[i][slot][1] = e1; r[i][slot][2] = e2;
    r[i][slot][3] = e3; r[i][slot][4] = e4;
  }
}

__global__ __launch_bounds__(256) void median5x5_kernel(
    const float* __restrict__ x, float* __restrict__ out) {
  int t = blockIdx.x * blockDim.x + threadIdx.x;

  if (t < N_INT) {
    // ---------------- interior fast path ----------------
    int gi = t % NG_I;
    int rest = t / NG_I;
    int hb = rest % HB;
    int b = rest / HB;
    int h0 = hb * RUN;
    int g4 = 4 * gi;                       // load base offset in row (= f - 8)

    const float* xb = x + b * Hn * WC;

    float ring[4][5][5];

    // prologue: rows h0-2 .. h0+1 -> slots 0..3
#pragma unroll
    for (int p = 0; p < 4; ++p) {
      float L[20];
      load20(xb + reflect_idx(h0 - 2 + p, Hn) * WC + g4, L);
      sort_into(ring, L, p);
    }

    // prefetch first compute row (h0+2)
    float L[20];
    load20(xb + reflect_idx(h0 + 2, Hn) * WC + g4, L);

    int orow = (b * Hn + h0) * WC + g4 + 8;

#pragma unroll
    for (int k = 0; k < RUN; ++k) {
      const int s = (k + 4) % 5;
      sort_into(ring, L, s);
      if (k + 1 < RUN)
        load20(xb + reflect_idx(h0 + k + 3, Hn) * WC + g4, L);
      const int q0 = (s + 1) % 5, q1 = (s + 2) % 5, q2 = (s + 3) % 5, q3 = (s + 4) % 5;
      float4 ov;
      ov.x = median25(ring[0][q0], ring[0][q1], ring[0][q2], ring[0][q3], ring[0][s]);
      ov.y = median25(ring[1][q0], ring[1][q1], ring[1][q2], ring[1][q3], ring[1][s]);
      ov.z = median25(ring[2][q0], ring[2][q1], ring[2][q2], ring[2][q3], ring[2][s]);
      ov.w = median25(ring[3][q0], ring[3][q1], ring[3][q2], ring[3][q3], ring[3][s]);
      *reinterpret_cast<float4*>(out + orow + k * WC) = ov;
    }
  } else {
    // ---------------- border columns (w reflection) ----------------
    int u = t - N_INT;
    int col = u % 16;
    int rest = u / 16;
    int hb = rest % HB;
    int b = rest / HB;
    int h0 = hb * RUN;
    int f = col < 8 ? col : (WC - 16 + col);   // 0..7 or 1144..1151
    int w = f / 3, c = f % 3;

    int ow[5];
#pragma unroll
    for (int j = 0; j < 5; ++j) ow[j] = reflect_idx(w + j - 2, Wn) * 3 + c;

    const float* xb = x + b * Hn * WC;

    float ring1[5][5];
#pragma unroll
    for (int p = 0; p < 4; ++p) {
      const float* rp = xb + reflect_idx(h0 - 2 + p, Hn) * WC;
      float e0 = rp[ow[0]], e1 = rp[ow[1]], e2 = rp[ow[2]], e3 = rp[ow[3]], e4 = rp[ow[4]];
      SORT5(e0, e1, e2, e3, e4);
      ring1[p][0] = e0; ring1[p][1] = e1; ring1[p][2] = e2; ring1[p][3] = e3; ring1[p][4] = e4;
    }

    int orow = (b * Hn + h0) * WC + f;
#pragma unroll
    for (int k = 0; k < RUN; ++k) {
      const float* rp = xb + reflect_idx(h0 + k + 2, Hn) * WC;
      float e0 = rp[ow[0]], e1 = rp[ow[1]], e2 = rp[ow[2]], e3 = rp[ow[3]], e4 = rp[ow[4]];
      SORT5(e0, e1, e2, e3, e4);
      const int s = (k + 4) % 5;
      ring1[s][0] = e0; ring1[s][1] = e1; ring1[s][2] = e2; ring1[s][3] = e3; ring1[s][4] = e4;
      const int q0 = (s + 1) % 5, q1 = (s + 2) % 5, q2 = (s + 3) % 5, q3 = (s + 4) % 5;
      out[orow + k * WC] = median25(ring1[q0], ring1[q1], ring1[q2], ring1[q3], ring1[s]);
    }
  }
}

extern "C" void kernel_launch(void* const* d_in, const int* in_sizes, int n_in,
                              void* d_out, int out_size, void* d_ws, size_t ws_size,
                              hipStream_t stream) {
  const float* x = (const float*)d_in[0];
  float* out = (float*)d_out;
  int total_threads = N_INT + N_BND;        // 460800 = 1800 * 256 exactly
  int block = 256;
  int grid = total_threads / block;         // 1800
  median5x5_kernel<<<grid, block, 0, stream>>>(x, out);
}

// Round 6
// 39.291 us; speedup vs baseline: 2.3451x; 1.0843x over previous
//
#include <hip/hip_runtime.h>

// 5x5 median, reflect padding, NHWC f32 (16,384,384,3).
// Interior thread = 2 consecutive flat columns (f, f+1; f even) x RUN=8 rows.
//   - Taps for flat col f are at stride C=3: {f-6,f-3,f,f+3,f+6}. The pair
//     (f, f+1) spans f-6..f+7 = 14 floats = 7 aligned float2 loads per row.
//   - Per-column ring of 5 sorted 5-windows, reused 5x vertically.
//   - median25: SORT4 of old rows + closed-form rank-insert of new row
//     (13 band cells, exact order statistics) + forgetful rank-7-of-13.
//     [validated R2-R4]
//   - float2 output stores.
// Border columns (w<2 or w>=382: flat 0..5, 1146..1151) in dedicated
// trailing blocks (block-uniform branch).

#define CAS(a, b) do { float _t = fminf(a, b); (b) = fmaxf(a, b); (a) = _t; } while (0)

#define SORT5(e0, e1, e2, e3, e4) do { \
  CAS(e0, e1); CAS(e3, e4); CAS(e2, e4); CAS(e2, e3); CAS(e1, e4); \
  CAS(e0, e3); CAS(e0, e2); CAS(e1, e3); CAS(e1, e2); } while (0)

#define SORT4(a, b, c, d) do { \
  CAS(a, b); CAS(c, d); CAS(a, c); CAS(b, d); CAS(b, c); } while (0)

__device__ __forceinline__ int reflect_idx(int v, int n) {
  v = v < 0 ? -v : v;
  v = v >= n ? 2 * n - 2 - v : v;
  return v;
}

// Exact median of 25. a,b,cc,d = older sorted 5-windows (order irrelevant),
// n = newest sorted 5-window.
__device__ __forceinline__ float median25(const float* a, const float* b,
                                          const float* cc, const float* d,
                                          const float* n) {
  float A1, A2, B1, B2, B3, C1, C2, C3, D1, D2, D3, E1, E2;
  { float p=a[0],q=b[0],r=cc[0],s=d[0],e=n[0]; SORT4(p,q,r,s);
    D1 = fmaxf(r, fminf(s, e)); E1 = fmaxf(s, e); }
  { float p=a[1],q=b[1],r=cc[1],s=d[1],e=n[1]; SORT4(p,q,r,s);
    C1 = fmaxf(q, fminf(r, e)); D2 = fmaxf(r, fminf(s, e)); E2 = fmaxf(s, e); }
  { float p=a[2],q=b[2],r=cc[2],s=d[2],e=n[2]; SORT4(p,q,r,s);
    B1 = fmaxf(p, fminf(q, e)); C2 = fmaxf(q, fminf(r, e)); D3 = fmaxf(r, fminf(s, e)); }
  { float p=a[3],q=b[3],r=cc[3],s=d[3],e=n[3]; SORT4(p,q,r,s);
    A1 = fminf(p, e); B2 = fminf(q, fmaxf(p, e)); C3 = fminf(r, fmaxf(q, e)); }
  { float p=a[4],q=b[4],r=cc[4],s=d[4],e=n[4]; SORT4(p,q,r,s);
    A2 = fminf(p, e); B3 = fminf(q, fmaxf(p, e)); }

  CAS(B3, C3);
  CAS(A1, B1); CAS(A1, C1);
  CAS(A2, B3); CAS(C2, D2); CAS(B3, D2);
  CAS(B1, C1); CAS(D1, A2); CAS(B1, D1);
  float s0 = C1, s1 = B2, s2 = B3, s3 = C2, s4 = A2, s5 = D1, s6 = D3, s7 = E1;
  CAS(s0, s1); CAS(s2, s3); CAS(s4, s5); CAS(s6, s7);
  CAS(s0, s2); CAS(s4, s6); CAS(s0, s4);
  CAS(s1, s3); CAS(s5, s7); CAS(s3, s7);
  float t0 = s1, t1 = s2, t2 = s3, t3 = s4, t4 = s5, t5 = s6, t6 = E2;
  CAS(t0, t1); CAS(t2, t3); CAS(t4, t5);
  CAS(t0, t2); CAS(t0, t4); CAS(t0, t6);
  CAS(t1, t3); CAS(t5, t6); CAS(t3, t6);
  CAS(t1, t2); CAS(t3, t4);
  CAS(t1, t3); CAS(t1, t5);
  CAS(t2, t4); CAS(t4, t5);
  CAS(t2, t3);
  return fmaxf(t2, fminf(t3, t4));
}

constexpr int RUN = 8;
constexpr int Bn = 16, Hn = 384, Wn = 384, Cn = 3;
constexpr int WC = Wn * Cn;              // 1152
constexpr int HB = Hn / RUN;             // 48
constexpr int NG_I = 570;                // pairs (f, f+1), f = 6 + 2*gi, f in [6,1144]
constexpr int N_INT = Bn * HB * NG_I;    // 437760 = 1710 * 256
constexpr int N_BND = Bn * HB * 12;      // 9216   = 36 * 256

__global__ __launch_bounds__(256) void median5x5_kernel(
    const float* __restrict__ x, float* __restrict__ out) {
  int t = blockIdx.x * blockDim.x + threadIdx.x;

  if (t < N_INT) {
    // ---------------- interior fast path ----------------
    int gi = t % NG_I;
    int rest = t / NG_I;
    int hb = rest % HB;
    int b = rest / HB;
    int h0 = hb * RUN;
    int f = 6 + 2 * gi;
    int fb = f - 6;                      // load base (even -> 8B aligned)

    const float* xb = x + b * Hn * WC + fb;

    float ring[2][5][5];

    // prologue: rows h0-2 .. h0+1 -> slots 0..3
#pragma unroll
    for (int p = 0; p < 4; ++p) {
      const float2* rp = reinterpret_cast<const float2*>(xb + reflect_idx(h0 - 2 + p, Hn) * WC);
      float2 v0 = rp[0], v1 = rp[1], v2 = rp[2], v3 = rp[3], v4 = rp[4], v5 = rp[5], v6 = rp[6];
      // col f taps (stride 3): L0 L3 L6 L9 L12
      float e0 = v0.x, e1 = v1.y, e2 = v3.x, e3 = v4.y, e4 = v6.x;
      // col f+1 taps: L1 L4 L7 L10 L13
      float f0 = v0.y, f1 = v2.x, f2 = v3.y, f3 = v5.x, f4 = v6.y;
      SORT5(e0, e1, e2, e3, e4);
      SORT5(f0, f1, f2, f3, f4);
      ring[0][p][0]=e0; ring[0][p][1]=e1; ring[0][p][2]=e2; ring[0][p][3]=e3; ring[0][p][4]=e4;
      ring[1][p][0]=f0; ring[1][p][1]=f1; ring[1][p][2]=f2; ring[1][p][3]=f3; ring[1][p][4]=f4;
    }

    // prefetch first compute row (h0+2)
    float2 v0, v1, v2, v3, v4, v5, v6;
    {
      const float2* rp = reinterpret_cast<const float2*>(xb + reflect_idx(h0 + 2, Hn) * WC);
      v0 = rp[0]; v1 = rp[1]; v2 = rp[2]; v3 = rp[3]; v4 = rp[4]; v5 = rp[5]; v6 = rp[6];
    }

    int orow = (b * Hn + h0) * WC + f;

#pragma unroll
    for (int k = 0; k < RUN; ++k) {
      const int s = (k + 4) % 5;          // compile-time after unroll
      float e0 = v0.x, e1 = v1.y, e2 = v3.x, e3 = v4.y, e4 = v6.x;
      float f0 = v0.y, f1 = v2.x, f2 = v3.y, f3 = v5.x, f4 = v6.y;
      SORT5(e0, e1, e2, e3, e4);
      SORT5(f0, f1, f2, f3, f4);
      ring[0][s][0]=e0; ring[0][s][1]=e1; ring[0][s][2]=e2; ring[0][s][3]=e3; ring[0][s][4]=e4;
      ring[1][s][0]=f0; ring[1][s][1]=f1; ring[1][s][2]=f2; ring[1][s][3]=f3; ring[1][s][4]=f4;

      if (k + 1 < RUN) {
        const float2* rp = reinterpret_cast<const float2*>(xb + reflect_idx(h0 + k + 3, Hn) * WC);
        v0 = rp[0]; v1 = rp[1]; v2 = rp[2]; v3 = rp[3]; v4 = rp[4]; v5 = rp[5]; v6 = rp[6];
      }

      const int q0 = (s + 1) % 5, q1 = (s + 2) % 5, q2 = (s + 3) % 5, q3 = (s + 4) % 5;
      float2 ov;
      ov.x = median25(ring[0][q0], ring[0][q1], ring[0][q2], ring[0][q3], ring[0][s]);
      ov.y = median25(ring[1][q0], ring[1][q1], ring[1][q2], ring[1][q3], ring[1][s]);
      *reinterpret_cast<float2*>(out + orow + k * WC) = ov;
    }
  } else {
    // ---------------- border columns (w reflection) ----------------
    int u = t - N_INT;
    int col = u % 12;
    int rest = u / 12;
    int hb = rest % HB;
    int b = rest / HB;
    int h0 = hb * RUN;
    int f = col < 6 ? col : (WC - 12 + col);   // 0..5 or 1146..1151
    int w = f / 3, c = f % 3;

    int ow[5];
#pragma unroll
    for (int j = 0; j < 5; ++j) ow[j] = reflect_idx(w + j - 2, Wn) * 3 + c;

    const float* xb = x + b * Hn * WC;

    float ring1[5][5];
#pragma unroll
    for (int p = 0; p < 4; ++p) {
      const float* rp = xb + reflect_idx(h0 - 2 + p, Hn) * WC;
      float e0 = rp[ow[0]], e1 = rp[ow[1]], e2 = rp[ow[2]], e3 = rp[ow[3]], e4 = rp[ow[4]];
      SORT5(e0, e1, e2, e3, e4);
      ring1[p][0]=e0; ring1[p][1]=e1; ring1[p][2]=e2; ring1[p][3]=e3; ring1[p][4]=e4;
    }

    int orow = (b * Hn + h0) * WC + f;
#pragma unroll
    for (int k = 0; k < RUN; ++k) {
      const float* rp = xb + reflect_idx(h0 + k + 2, Hn) * WC;
      float e0 = rp[ow[0]], e1 = rp[ow[1]], e2 = rp[ow[2]], e3 = rp[ow[3]], e4 = rp[ow[4]];
      SORT5(e0, e1, e2, e3, e4);
      const int s = (k + 4) % 5;
      ring1[s][0]=e0; ring1[s][1]=e1; ring1[s][2]=e2; ring1[s][3]=e3; ring1[s][4]=e4;
      const int q0 = (s + 1) % 5, q1 = (s + 2) % 5, q2 = (s + 3) % 5, q3 = (s + 4) % 5;
      out[orow + k * WC] = median25(ring1[q0], ring1[q1], ring1[q2], ring1[q3], ring1[s]);
    }
  }
}

extern "C" void kernel_launch(void* const* d_in, const int* in_sizes, int n_in,
                              void* d_out, int out_size, void* d_ws, size_t ws_size,
                              hipStream_t stream) {
  const float* x = (const float*)d_in[0];
  float* out = (float*)d_out;
  int total_threads = N_INT + N_BND;        // 446976 = 1746 * 256 exactly
  int block = 256;
  int grid = total_threads / block;         // 1746
  median5x5_kernel<<<grid, block, 0, stream>>>(x, out);
}